// Round 5
// baseline (163.034 us; speedup 1.0000x reference)
//
#include <hip/hip_runtime.h>

#define T_LEN 2048
#define NSTATE 64
#define NCHUNK 16
#define CH_S 128      // stored steps per chunk = LDS buffer depth
#define WARM 64       // warm-up steps before/after the stored region
#define RK 16         // renorm every 16 steps (scale cancels in LLR)

// v_add_f32 with DPP-modified src: single fused VALU instr, no DS op.
template<int CTRL>
__device__ __forceinline__ float dpp_add(float v) {
    int r = __builtin_amdgcn_update_dpp(0, __float_as_int(v), CTRL, 0xF, 0xF, true);
    return v + __int_as_float(r);
}

// v_mov_b32_dpp quad_perm [1,0,3,2]: value of lane^1 — VALU, no DS op.
__device__ __forceinline__ float dpp_mov_xor1(float v) {
    return __int_as_float(__builtin_amdgcn_update_dpp(0, __float_as_int(v), 0xB1, 0xF, 0xF, true));
}

// Pure-DPP 64-lane sum to lane 63 (row_shr 1,2,4,8 + row_bcast15/31). Zero DS.
__device__ __forceinline__ float dpp_sum_to63(float v) {
    v = dpp_add<0x111>(v);
    v = dpp_add<0x112>(v);
    v = dpp_add<0x114>(v);
    v = dpp_add<0x118>(v);
    v = dpp_add<0x142>(v);
    v = dpp_add<0x143>(v);
    return v;
}

// Full-wave sum broadcast via v_readlane — zero DS ops.
__device__ __forceinline__ float wave_total(float v) {
    float s = dpp_sum_to63(v);
    return __int_as_float(__builtin_amdgcn_readlane(__float_as_int(s), 63));
}

// v + v[lane^1] via DPP quad_perm [1,0,3,2].
__device__ __forceinline__ float pair_sum_xor1(float v) {
    int r = __builtin_amdgcn_update_dpp(0, __float_as_int(v), 0xB1, 0xF, 0xF, true);
    return v + __int_as_float(r);
}

// raw bpermute: addrb is BYTE address (src_lane*4)
__device__ __forceinline__ float bperm(int addrb, float v) {
    return __int_as_float(__builtin_amdgcn_ds_bpermute(addrb, __float_as_int(v)));
}

// cheap fp32 -> bf16 (round-half-up)
__device__ __forceinline__ unsigned short bf16_of(float f) {
    return (unsigned short)((__float_as_uint(f) + 0x8000u) >> 16);
}

// GEN_POLY = ('1111001','1011011'), mu=6, NS=64.
// o0 parity mask 57, o1 mask 27. x_s = kE*(la + c0(s)*l0 + c1(s)*l1),
// gamma(s,0)=2^x, gamma(s,1)=2^-x, to(s,b)=(b<<5)|(s>>1), kE=0.5*log2(e).

// ---- fwd 16-step group; stores alpha_t (bf16) into LDS when STORE ----
// One DS op on the chain: pre-select (even lane: gamma0 pair-sum, odd: gamma1
// pair-sum), then a single fixed bperm  dest j <- lane 2(j&31)+(j>>5).
template<bool STORE>
__device__ __forceinline__ float fwd_group(float state,
                                           const float* __restrict__ chp,
                                           const float* __restrict__ lap,
                                           unsigned short* __restrict__ alds,
                                           int g, int t0, int lane,
                                           float kE, float k0, float k1,
                                           int fselb)
{
    #pragma unroll
    for (int h = 0; h < 2; ++h) {
        const int gb = g + 8 * h;
        const float4* c4 = (const float4*)(chp + 2 * gb);
        const float4* a4 = (const float4*)(lap + gb);
        float4 cc[4], aa[2];
        #pragma unroll
        for (int i = 0; i < 4; ++i) cc[i] = c4[i];
        #pragma unroll
        for (int i = 0; i < 2; ++i) aa[i] = a4[i];
        #pragma unroll
        for (int i = 0; i < 8; ++i) {
            float l0 = (i & 1) ? cc[i >> 1].z : cc[i >> 1].x;
            float l1 = (i & 1) ? cc[i >> 1].w : cc[i >> 1].y;
            float la = ((const float*)aa)[i];
            if (STORE) alds[(gb + i - t0) * NSTATE + lane] = bf16_of(state);
            float x   = fmaf(la, kE, fmaf(l0, k0, l1 * k1));
            float g0v = exp2f(x);
            float g1v = __builtin_amdgcn_rcpf(g0v);
            float s0  = pair_sum_xor1(state * g0v);
            float s1  = pair_sum_xor1(state * g1v);
            float v   = (lane & 1) ? s1 : s0;     // even lane: s0, odd: s1
            state = bperm(fselb, v);              // dest j <- lane 2(j&31)+(j>>5)
        }
    }
    float s = wave_total(state);
    return state * __builtin_amdgcn_rcpf(s);
}

// ---- bwd 16-step group; fused LLR from LDS alpha when LLR ----
// One bperm/step: even lane fetches beta[m], odd fetches beta[m+32] (m=lane>>1);
// partner value via DPP xor1. gamma role-swap folded into sign bit of x:
//   ga = 2^(x ^ parity), gb = 1/ga  ->  beta_new = ga*a + gb*b  (exact old math).
template<bool LLR>
__device__ __forceinline__ float bwd_group(float state,
                                           const float* __restrict__ chp,
                                           const float* __restrict__ lap,
                                           const unsigned short* __restrict__ alds,
                                           float* __restrict__ outp,
                                           int g, int t0, int lane,
                                           float kE, float k0, float k1,
                                           unsigned pmask, int bgb)
{
    const bool odd = (lane & 1);
    #pragma unroll
    for (int h = 1; h >= 0; --h) {
        const int gb = g + 8 * h;
        const float4* c4 = (const float4*)(chp + 2 * gb);
        const float4* a4 = (const float4*)(lap + gb);
        float4 cc[4], aa[2];
        #pragma unroll
        for (int i = 0; i < 4; ++i) cc[i] = c4[i];
        #pragma unroll
        for (int i = 0; i < 2; ++i) aa[i] = a4[i];
        float av[8];
        if (LLR) {
            #pragma unroll
            for (int i = 0; i < 8; ++i)
                av[i] = __uint_as_float(((unsigned)alds[(gb + i - t0) * NSTATE + lane]) << 16);
        }
        #pragma unroll
        for (int i = 7; i >= 0; --i) {
            float l0 = (i & 1) ? cc[i >> 1].z : cc[i >> 1].x;
            float l1 = (i & 1) ? cc[i >> 1].w : cc[i >> 1].y;
            float la = ((const float*)aa)[i];
            float x  = fmaf(la, kE, fmaf(l0, k0, l1 * k1));
            float xg = __uint_as_float(__float_as_uint(x) ^ pmask);
            float ga = exp2f(xg);                      // even: gamma0, odd: gamma1
            float gb_ = __builtin_amdgcn_rcpf(ga);     // even: gamma1, odd: gamma0
            float a  = bperm(bgb, state);              // even: beta[m], odd: beta[m+32]
            float bb = dpp_mov_xor1(a);                // partner value
            float u0 = ga * a;
            float u1 = gb_ * bb;
            if (LLR) {
                float p0 = odd ? u1 : u0;              // gamma0 * beta[to0(s)]
                float p1 = odd ? u0 : u1;              // gamma1 * beta[to1(s)]
                float na = av[i] * p0;
                float nb = av[i] * p1;
                na += __shfl_xor(na, 32, 64);
                nb += __shfl_xor(nb, 32, 64);
                float z = (lane >= 32) ? nb : na;      // lo half: n0, hi half: n1
                z = dpp_add<0xB1>(z);                  // xor1
                z = dpp_add<0x4E>(z);                  // xor2
                z = dpp_add<0x124>(z);                 // row_ror:4
                z = dpp_add<0x128>(z);                 // row_ror:8 -> row-of-16 sums
                z += __shfl_xor(z, 16, 64);            // halves complete
                float lg = __log2f(z);                 // one log covers n0 AND n1
                float d  = (lg - __shfl_xor(lg, 32, 64)) * 0.6931471805599453f;
                if (lane == 0) outp[gb + i] = d;
            }
            state = u0 + u1;                           // beta_t
        }
    }
    float s = wave_total(state);
    return state * __builtin_amdgcn_rcpf(s);
}

// ---------------- Fused kernel: wave 0 = fwd (alpha->LDS), wave 1 = bwd+LLR ----------------
__global__ __launch_bounds__(128, 8)
void bcjr_fused_kernel(const float* __restrict__ llr_ch,   // [B][2*T]
                       const float* __restrict__ llr_a,    // [B][T]
                       float* __restrict__ out)            // [B][T]
{
    __shared__ unsigned short alds[CH_S * NSTATE];   // 16 KiB

    const int lane  = threadIdx.x & 63;
    const int role  = threadIdx.x >> 6;
    const int unit  = blockIdx.x;
    const int chunk = unit & (NCHUNK - 1);
    const int b     = unit >> 4;

    const float c0 = 1.0f - 2.0f * (float)(__popc(lane & 57) & 1);
    const float c1 = 1.0f - 2.0f * (float)(__popc(lane & 27) & 1);
    const float kE = 0.5f * 1.442695040888963f;
    const float k0 = kE * c0, k1 = kE * c1;

    const float* chp = llr_ch + (size_t)b * (2 * T_LEN);
    const float* lap = llr_a  + (size_t)b * T_LEN;
    const int t0 = chunk * CH_S;

    if (role == 0) {
        // ---- forward wave ----
        const int fselb = (2 * (lane & 31) + (lane >> 5)) << 2;
        float state = (chunk == 0) ? ((lane == 0) ? 1.0f : 0.0f) : (1.0f / 64.0f);
        const int ts = (chunk == 0) ? t0 : t0 - WARM;
        for (int g = ts; g < t0; g += RK)
            state = fwd_group<false>(state, chp, lap, alds, g, t0, lane, kE, k0, k1, fselb);
        for (int g = t0; g < t0 + CH_S; g += RK)
            state = fwd_group<true>(state, chp, lap, alds, g, t0, lane, kE, k0, k1, fselb);
        __syncthreads();   // publish alpha
    } else {
        // ---- backward wave ----
        const unsigned pmask = (unsigned)(lane & 1) << 31;
        const int bgb = ((lane >> 1) + ((lane & 1) << 5)) << 2;  // src lane * 4
        float state = 1.0f / 64.0f;          // exact beta_T for the last chunk
        const int te = (chunk == NCHUNK - 1) ? (t0 + CH_S) : (t0 + CH_S + WARM);
        for (int g = te - RK; g >= t0 + CH_S; g -= RK)
            state = bwd_group<false>(state, chp, lap, alds, nullptr, g, t0, lane, kE, k0, k1, pmask, bgb);
        __syncthreads();   // wait for alpha
        float* outp = out + (size_t)b * T_LEN;
        for (int g = t0 + CH_S - RK; g >= t0; g -= RK)
            state = bwd_group<true>(state, chp, lap, alds, outp, g, t0, lane, kE, k0, k1, pmask, bgb);
    }
}

extern "C" void kernel_launch(void* const* d_in, const int* in_sizes, int n_in,
                              void* d_out, int out_size, void* d_ws, size_t ws_size,
                              hipStream_t stream) {
    const float* llr_ch = (const float*)d_in[0];
    const float* llr_a  = (const float*)d_in[1];
    float* out = (float*)d_out;

    int B = in_sizes[0] / (2 * T_LEN);   // 256
    (void)d_ws; (void)ws_size;

    int n_units = B * NCHUNK;            // 4096 blocks (1 chunk each, 2 waves)
    hipLaunchKernelGGL(bcjr_fused_kernel, dim3(n_units), dim3(128), 0, stream,
                       llr_ch, llr_a, out);
}

// Round 6
// 158.328 us; speedup vs baseline: 1.0297x; 1.0297x over previous
//
#include <hip/hip_runtime.h>

#define T_LEN 2048
#define NSTATE 64
#define NCHUNK 32
#define CH_S 64       // stored steps per chunk = LDS buffer depth
#define WARM 64       // warm-up steps before/after the stored region
#define RK 16         // renorm every 16 steps (scale cancels in LLR)

// v_add_f32 with DPP-modified src: single fused VALU instr, no DS op.
template<int CTRL>
__device__ __forceinline__ float dpp_add(float v) {
    int r = __builtin_amdgcn_update_dpp(0, __float_as_int(v), CTRL, 0xF, 0xF, true);
    return v + __int_as_float(r);
}

// v_mov_b32_dpp quad_perm [1,0,3,2]: value of lane^1 — VALU, no DS op.
__device__ __forceinline__ float dpp_mov_xor1(float v) {
    return __int_as_float(__builtin_amdgcn_update_dpp(0, __float_as_int(v), 0xB1, 0xF, 0xF, true));
}

// Pure-DPP 64-lane sum to lane 63 (row_shr 1,2,4,8 + row_bcast15/31). Zero DS.
__device__ __forceinline__ float dpp_sum_to63(float v) {
    v = dpp_add<0x111>(v);
    v = dpp_add<0x112>(v);
    v = dpp_add<0x114>(v);
    v = dpp_add<0x118>(v);
    v = dpp_add<0x142>(v);
    v = dpp_add<0x143>(v);
    return v;
}

// Full-wave sum broadcast via v_readlane — zero DS ops.
__device__ __forceinline__ float wave_total(float v) {
    float s = dpp_sum_to63(v);
    return __int_as_float(__builtin_amdgcn_readlane(__float_as_int(s), 63));
}

// v + v[lane^1] via DPP quad_perm [1,0,3,2].
__device__ __forceinline__ float pair_sum_xor1(float v) {
    int r = __builtin_amdgcn_update_dpp(0, __float_as_int(v), 0xB1, 0xF, 0xF, true);
    return v + __int_as_float(r);
}

// raw bpermute: addrb is BYTE address (src_lane*4)
__device__ __forceinline__ float bperm(int addrb, float v) {
    return __int_as_float(__builtin_amdgcn_ds_bpermute(addrb, __float_as_int(v)));
}

// cheap fp32 -> bf16 (round-half-up)
__device__ __forceinline__ unsigned short bf16_of(float f) {
    return (unsigned short)((__float_as_uint(f) + 0x8000u) >> 16);
}
__device__ __forceinline__ float bf16_ld(const unsigned short* p) {
    return __uint_as_float(((unsigned)*p) << 16);
}

// GEN_POLY = ('1111001','1011011'), mu=6, NS=64.
// o0 parity mask 57, o1 mask 27. x_s = kE*(la + c0(s)*l0 + c1(s)*l1),
// gamma(s,0)=2^x, gamma(s,1)=2^-x, to(s,b)=(b<<5)|(s>>1), kE=0.5*log2(e).

// ---- fwd 16-step group; stores alpha_t (bf16) into LDS when STORE ----
// One DS op on the chain: pre-select (even lane: gamma0 pair-sum, odd: gamma1
// pair-sum), then a single fixed bperm  dest j <- lane 2(j&31)+(j>>5).
template<bool STORE>
__device__ __forceinline__ float fwd_group(float state,
                                           const float* __restrict__ chp,
                                           const float* __restrict__ lap,
                                           unsigned short* __restrict__ alds,
                                           int g, int t0, int lane,
                                           float kE, float k0, float k1,
                                           int fselb)
{
    #pragma unroll
    for (int h = 0; h < 2; ++h) {
        const int gb = g + 8 * h;
        const float4* c4 = (const float4*)(chp + 2 * gb);
        const float4* a4 = (const float4*)(lap + gb);
        float4 cc[4], aa[2];
        #pragma unroll
        for (int i = 0; i < 4; ++i) cc[i] = c4[i];
        #pragma unroll
        for (int i = 0; i < 2; ++i) aa[i] = a4[i];
        #pragma unroll
        for (int i = 0; i < 8; ++i) {
            float l0 = (i & 1) ? cc[i >> 1].z : cc[i >> 1].x;
            float l1 = (i & 1) ? cc[i >> 1].w : cc[i >> 1].y;
            float la = ((const float*)aa)[i];
            if (STORE) alds[(gb + i - t0) * NSTATE + lane] = bf16_of(state);
            float x   = fmaf(la, kE, fmaf(l0, k0, l1 * k1));
            float g0v = exp2f(x);
            float g1v = __builtin_amdgcn_rcpf(g0v);
            float s0  = pair_sum_xor1(state * g0v);
            float s1  = pair_sum_xor1(state * g1v);
            float v   = (lane & 1) ? s1 : s0;     // even lane: s0, odd: s1
            state = bperm(fselb, v);              // dest j <- lane 2(j&31)+(j>>5)
        }
    }
    float s = wave_total(state);
    return state * __builtin_amdgcn_rcpf(s);
}

// ---- bwd 16-step group (light); stores beta_{t+1} (bf16) into LDS when STORE ----
// One bperm/step: even lane fetches beta[m], odd fetches beta[m+32] (m=lane>>1);
// partner via DPP xor1. gamma role-swap folded into sign bit of x.
template<bool STORE>
__device__ __forceinline__ float bwd_group(float state,
                                           const float* __restrict__ chp,
                                           const float* __restrict__ lap,
                                           unsigned short* __restrict__ blds,
                                           int g, int t0, int lane,
                                           float kE, float k0, float k1,
                                           unsigned pmask, int bgb)
{
    #pragma unroll
    for (int h = 1; h >= 0; --h) {
        const int gb = g + 8 * h;
        const float4* c4 = (const float4*)(chp + 2 * gb);
        const float4* a4 = (const float4*)(lap + gb);
        float4 cc[4], aa[2];
        #pragma unroll
        for (int i = 0; i < 4; ++i) cc[i] = c4[i];
        #pragma unroll
        for (int i = 0; i < 2; ++i) aa[i] = a4[i];
        #pragma unroll
        for (int i = 7; i >= 0; --i) {
            float l0 = (i & 1) ? cc[i >> 1].z : cc[i >> 1].x;
            float l1 = (i & 1) ? cc[i >> 1].w : cc[i >> 1].y;
            float la = ((const float*)aa)[i];
            // state here = beta_{t+1} for t = gb+i: store BEFORE the update
            if (STORE) blds[(gb + i - t0) * NSTATE + lane] = bf16_of(state);
            float x  = fmaf(la, kE, fmaf(l0, k0, l1 * k1));
            float xg = __uint_as_float(__float_as_uint(x) ^ pmask);
            float ga = exp2f(xg);                      // even: gamma0, odd: gamma1
            float gb_ = __builtin_amdgcn_rcpf(ga);     // even: gamma1, odd: gamma0
            float a  = bperm(bgb, state);              // even: beta[m], odd: beta[m+32]
            float bb = dpp_mov_xor1(a);                // partner value
            state = fmaf(ga, a, gb_ * bb);             // beta_t
        }
    }
    float s = wave_total(state);
    return state * __builtin_amdgcn_rcpf(s);
}

// ---------------- Fused kernel ----------------
// Phase 1 (parallel, balanced): wave 0 = fwd sweep (alpha->LDS),
//                               wave 1 = bwd sweep (beta->LDS). Equal length.
// Barrier.
// Phase 2 (parallel, independent steps): each wave computes LLR for 32 of the
// 64 stored t's, reading alpha/beta from LDS (arbitrary index, no shuffles
// on data-dependent paths).
__global__ __launch_bounds__(128, 8)
void bcjr_fused_kernel(const float* __restrict__ llr_ch,   // [B][2*T]
                       const float* __restrict__ llr_a,    // [B][T]
                       float* __restrict__ out)            // [B][T]
{
    __shared__ unsigned short alds[CH_S * NSTATE];   // 8 KiB: alpha_t
    __shared__ unsigned short blds[CH_S * NSTATE];   // 8 KiB: beta_{t+1}

    const int lane  = threadIdx.x & 63;
    const int role  = threadIdx.x >> 6;
    const int unit  = blockIdx.x;
    const int chunk = unit & (NCHUNK - 1);
    const int b     = unit >> 5;

    const float c0 = 1.0f - 2.0f * (float)(__popc(lane & 57) & 1);
    const float c1 = 1.0f - 2.0f * (float)(__popc(lane & 27) & 1);
    const float kE = 0.5f * 1.442695040888963f;
    const float k0 = kE * c0, k1 = kE * c1;

    const float* chp = llr_ch + (size_t)b * (2 * T_LEN);
    const float* lap = llr_a  + (size_t)b * T_LEN;
    const int t0 = chunk * CH_S;

    if (role == 0) {
        // ---- forward sweep ----
        const int fselb = (2 * (lane & 31) + (lane >> 5)) << 2;
        float state = (chunk == 0) ? ((lane == 0) ? 1.0f : 0.0f) : (1.0f / 64.0f);
        const int ts = (chunk == 0) ? t0 : t0 - WARM;
        for (int g = ts; g < t0; g += RK)
            state = fwd_group<false>(state, chp, lap, alds, g, t0, lane, kE, k0, k1, fselb);
        for (int g = t0; g < t0 + CH_S; g += RK)
            state = fwd_group<true>(state, chp, lap, alds, g, t0, lane, kE, k0, k1, fselb);
    } else {
        // ---- backward sweep ----
        const unsigned pmask = (unsigned)(lane & 1) << 31;
        const int bgb = ((lane >> 1) + ((lane & 1) << 5)) << 2;  // src lane * 4
        float state = 1.0f / 64.0f;          // exact beta_T for the last chunk
        const int te = (chunk == NCHUNK - 1) ? (t0 + CH_S) : (t0 + CH_S + WARM);
        for (int g = te - RK; g >= t0 + CH_S; g -= RK)
            state = bwd_group<false>(state, chp, lap, blds, g, t0, lane, kE, k0, k1, pmask, bgb);
        for (int g = t0 + CH_S - RK; g >= t0; g -= RK)
            state = bwd_group<true>(state, chp, lap, blds, g, t0, lane, kE, k0, k1, pmask, bgb);
    }

    __syncthreads();   // alpha & beta published

    // ---- LLR phase: 64 independent steps, 32 per wave ----
    {
        float* outp = out + (size_t)b * T_LEN;
        const int base = role * (CH_S / 2);          // 0 or 32 within chunk
        #pragma unroll 4
        for (int ii = 0; ii < CH_S / 2; ++ii) {
            const int tt = base + ii;                // slot within chunk
            const int t  = t0 + tt;
            float2 cv = ((const float2*)chp)[t];
            float la  = lap[t];
            float x   = fmaf(la, kE, fmaf(cv.x, k0, cv.y * k1));
            float g0v = exp2f(x);
            float g1v = __builtin_amdgcn_rcpf(g0v);
            float av  = bf16_ld(&alds[tt * NSTATE + lane]);
            float b0v = bf16_ld(&blds[tt * NSTATE + (lane >> 1)]);
            float b1v = bf16_ld(&blds[tt * NSTATE + 32 + (lane >> 1)]);
            float na  = (av * g0v) * b0v;            // n0 partial of state s=lane
            float nb  = (av * g1v) * b1v;            // n1 partial
            na += __shfl_xor(na, 32, 64);
            nb += __shfl_xor(nb, 32, 64);
            float z = (lane >= 32) ? nb : na;        // lo half: n0, hi half: n1
            z = dpp_add<0xB1>(z);                    // xor1
            z = dpp_add<0x4E>(z);                    // xor2
            z = dpp_add<0x124>(z);                   // row_ror:4
            z = dpp_add<0x128>(z);                   // row_ror:8 -> row-of-16 sums
            z += __shfl_xor(z, 16, 64);              // halves complete
            float lg = __log2f(z);                   // one log covers n0 AND n1
            float d  = (lg - __shfl_xor(lg, 32, 64)) * 0.6931471805599453f;
            if (lane == 0) outp[t] = d;              // llr_t
        }
    }
}

extern "C" void kernel_launch(void* const* d_in, const int* in_sizes, int n_in,
                              void* d_out, int out_size, void* d_ws, size_t ws_size,
                              hipStream_t stream) {
    const float* llr_ch = (const float*)d_in[0];
    const float* llr_a  = (const float*)d_in[1];
    float* out = (float*)d_out;

    int B = in_sizes[0] / (2 * T_LEN);   // 256
    (void)d_ws; (void)ws_size;

    int n_units = B * NCHUNK;            // 8192 blocks (1 chunk each, 2 waves)
    hipLaunchKernelGGL(bcjr_fused_kernel, dim3(n_units), dim3(128), 0, stream,
                       llr_ch, llr_a, out);
}

// Round 7
// 131.559 us; speedup vs baseline: 1.2392x; 1.2035x over previous
//
#include <hip/hip_runtime.h>

#define T_LEN 2048
#define NSTATE 64
#define NCHUNK 16
#define CH_S 128      // stored steps per chunk
#define HF 64         // half of stored region (LDS depth per trajectory)
#define WARM 64       // warm-up steps before/after the stored region
#define RK 16         // renorm every 16 steps (scale cancels in LLR)

// v_add_f32 with DPP-modified src: single fused VALU instr, no DS op.
template<int CTRL>
__device__ __forceinline__ float dpp_add(float v) {
    int r = __builtin_amdgcn_update_dpp(0, __float_as_int(v), CTRL, 0xF, 0xF, true);
    return v + __int_as_float(r);
}

// v_mov_b32_dpp quad_perm [1,0,3,2]: value of lane^1 — VALU, no DS op.
__device__ __forceinline__ float dpp_mov_xor1(float v) {
    return __int_as_float(__builtin_amdgcn_update_dpp(0, __float_as_int(v), 0xB1, 0xF, 0xF, true));
}

// Pure-DPP 64-lane sum to lane 63 (row_shr 1,2,4,8 + row_bcast15/31). Zero DS.
__device__ __forceinline__ float dpp_sum_to63(float v) {
    v = dpp_add<0x111>(v);
    v = dpp_add<0x112>(v);
    v = dpp_add<0x114>(v);
    v = dpp_add<0x118>(v);
    v = dpp_add<0x142>(v);
    v = dpp_add<0x143>(v);
    return v;
}

// Full-wave sum broadcast via v_readlane — zero DS ops.
__device__ __forceinline__ float wave_total(float v) {
    float s = dpp_sum_to63(v);
    return __int_as_float(__builtin_amdgcn_readlane(__float_as_int(s), 63));
}

// v + v[lane^1] via DPP quad_perm [1,0,3,2].
__device__ __forceinline__ float pair_sum_xor1(float v) {
    int r = __builtin_amdgcn_update_dpp(0, __float_as_int(v), 0xB1, 0xF, 0xF, true);
    return v + __int_as_float(r);
}

// raw bpermute: addrb is BYTE address (src_lane*4)
__device__ __forceinline__ float bperm(int addrb, float v) {
    return __int_as_float(__builtin_amdgcn_ds_bpermute(addrb, __float_as_int(v)));
}

// cheap fp32 -> bf16 (round-half-up)
__device__ __forceinline__ unsigned short bf16_of(float f) {
    return (unsigned short)((__float_as_uint(f) + 0x8000u) >> 16);
}
__device__ __forceinline__ float bf16_ld(const unsigned short* p) {
    return __uint_as_float(((unsigned)*p) << 16);
}

// Dual reduction (n0 over all lanes, n1 over all lanes) sharing one tree and
// one log: fold xor32, route n0->low half / n1->high half, 4 DPP levels +
// xor16, log2, subtract across xor32. Verified rounds 1/3/5/6.
__device__ __forceinline__ void llr_reduce_store(float na, float nb, int lane, float* dst) {
    na += __shfl_xor(na, 32, 64);
    nb += __shfl_xor(nb, 32, 64);
    float z = (lane >= 32) ? nb : na;
    z = dpp_add<0xB1>(z);                  // xor1
    z = dpp_add<0x4E>(z);                  // xor2
    z = dpp_add<0x124>(z);                 // row_ror:4
    z = dpp_add<0x128>(z);                 // row_ror:8 -> row-of-16 sums
    z += __shfl_xor(z, 16, 64);            // halves complete
    float lg = __log2f(z);
    float d  = (lg - __shfl_xor(lg, 32, 64)) * 0.6931471805599453f;
    if (lane == 0) *dst = d;
}

// GEN_POLY = ('1111001','1011011'), mu=6, NS=64.
// o0 parity mask 57, o1 mask 27. x_s = kE*(la + c0(s)*l0 + c1(s)*l1),
// gamma(s,0)=2^x, gamma(s,1)=2^-x, to(s,b)=(b<<5)|(s>>1), kE=0.5*log2(e).

// ---- fwd 16-step group. MODE: 0=light, 1=store alpha(H0), 2=heavy LLR(H1) ----
// One DS op on the chain: pre-select pair-sums, single fixed bperm
// dest j <- lane 2(j&31)+(j>>5). Heavy mode reuses sg0/sg1 = alpha*gamma for
// the LLR numerators (no extra gamma work).
template<int MODE>
__device__ __forceinline__ float fwd_group(float state,
                                           const float* __restrict__ chp,
                                           const float* __restrict__ lap,
                                           unsigned short* __restrict__ alds,
                                           const unsigned short* __restrict__ blds,
                                           float* __restrict__ outp,
                                           int g, int t0, int lane,
                                           float kE, float k0, float k1,
                                           int fselb)
{
    #pragma unroll
    for (int h = 0; h < 2; ++h) {
        const int gb = g + 8 * h;
        const float4* c4 = (const float4*)(chp + 2 * gb);
        const float4* a4 = (const float4*)(lap + gb);
        float4 cc[4], aa[2];
        #pragma unroll
        for (int i = 0; i < 4; ++i) cc[i] = c4[i];
        #pragma unroll
        for (int i = 0; i < 2; ++i) aa[i] = a4[i];
        float bv0[8], bv1[8];
        if (MODE == 2) {
            // beta_{t+1} for the 8 steps (stored by bwd wave), batched reads
            const unsigned short* bp = blds + (size_t)(gb - t0 - HF) * NSTATE + (lane >> 1);
            #pragma unroll
            for (int i = 0; i < 8; ++i) {
                bv0[i] = bf16_ld(bp + i * NSTATE);        // beta[to0(s)] = beta[s>>1]
                bv1[i] = bf16_ld(bp + i * NSTATE + 32);   // beta[to1(s)] = beta[32+(s>>1)]
            }
        }
        #pragma unroll
        for (int i = 0; i < 8; ++i) {
            float l0 = (i & 1) ? cc[i >> 1].z : cc[i >> 1].x;
            float l1 = (i & 1) ? cc[i >> 1].w : cc[i >> 1].y;
            float la = ((const float*)aa)[i];
            if (MODE == 1) alds[(gb + i - t0) * NSTATE + lane] = bf16_of(state);
            float x   = fmaf(la, kE, fmaf(l0, k0, l1 * k1));
            float g0v = exp2f(x);
            float g1v = __builtin_amdgcn_rcpf(g0v);
            float sg0 = state * g0v;             // alpha_t[s]*gamma0(s)
            float sg1 = state * g1v;             // alpha_t[s]*gamma1(s)
            if (MODE == 2)
                llr_reduce_store(sg0 * bv0[i], sg1 * bv1[i], lane, outp + gb + i);
            float s0 = pair_sum_xor1(sg0);
            float s1 = pair_sum_xor1(sg1);
            float v  = (lane & 1) ? s1 : s0;     // even lane: s0, odd: s1
            state = bperm(fselb, v);             // dest j <- lane 2(j&31)+(j>>5)
        }
    }
    float s = wave_total(state);
    return state * __builtin_amdgcn_rcpf(s);
}

// ---- bwd 16-step group. MODE: 0=light, 1=store beta(H1), 2=heavy LLR(H0) ----
// One bperm/step: even lane fetches beta[m], odd beta[m+32] (m=lane>>1);
// partner via DPP xor1. gamma role-swap folded into sign bit of x.
template<int MODE>
__device__ __forceinline__ float bwd_group(float state,
                                           const float* __restrict__ chp,
                                           const float* __restrict__ lap,
                                           const unsigned short* __restrict__ alds,
                                           unsigned short* __restrict__ blds,
                                           float* __restrict__ outp,
                                           int g, int t0, int lane,
                                           float kE, float k0, float k1,
                                           unsigned pmask, int bgb)
{
    const bool odd = (lane & 1);
    #pragma unroll
    for (int h = 1; h >= 0; --h) {
        const int gb = g + 8 * h;
        const float4* c4 = (const float4*)(chp + 2 * gb);
        const float4* a4 = (const float4*)(lap + gb);
        float4 cc[4], aa[2];
        #pragma unroll
        for (int i = 0; i < 4; ++i) cc[i] = c4[i];
        #pragma unroll
        for (int i = 0; i < 2; ++i) aa[i] = a4[i];
        float av[8];
        if (MODE == 2) {
            // alpha_t for the 8 steps (stored by fwd wave), batched reads
            const unsigned short* ap = alds + (size_t)(gb - t0) * NSTATE + lane;
            #pragma unroll
            for (int i = 0; i < 8; ++i)
                av[i] = bf16_ld(ap + i * NSTATE);
        }
        #pragma unroll
        for (int i = 7; i >= 0; --i) {
            float l0 = (i & 1) ? cc[i >> 1].z : cc[i >> 1].x;
            float l1 = (i & 1) ? cc[i >> 1].w : cc[i >> 1].y;
            float la = ((const float*)aa)[i];
            // state here = beta_{t+1} for t = gb+i: store BEFORE the update
            if (MODE == 1) blds[(gb + i - t0 - HF) * NSTATE + lane] = bf16_of(state);
            float x  = fmaf(la, kE, fmaf(l0, k0, l1 * k1));
            float xg = __uint_as_float(__float_as_uint(x) ^ pmask);
            float ga  = exp2f(xg);                     // even: gamma0, odd: gamma1
            float gb_ = __builtin_amdgcn_rcpf(ga);     // even: gamma1, odd: gamma0
            float a  = bperm(bgb, state);              // even: beta[m], odd: beta[m+32]
            float bb = dpp_mov_xor1(a);                // partner value
            float u0 = ga * a;
            float u1 = gb_ * bb;
            if (MODE == 2) {
                float ua = odd ? u1 : u0;              // gamma0*beta[to0(s)]
                float ub = odd ? u0 : u1;              // gamma1*beta[to1(s)]
                llr_reduce_store(av[i] * ua, av[i] * ub, lane, outp + gb + i);
            }
            state = u0 + u1;                           // beta_t
        }
    }
    float s = wave_total(state);
    return state * __builtin_amdgcn_rcpf(s);
}

// ---------------- Fused kernel: staggered half-chunks ----------------
// Segment A (balanced, 128 steps each): fwd = warm + stored-H0 (alpha->LDS);
//                                       bwd = warm + stored-H1 (beta->LDS).
// Barrier.
// Segment B (balanced, 64 steps each):  fwd sweeps H1 w/ inline LLR (beta
//                                       from LDS); bwd sweeps H0 w/ inline
//                                       LLR (alpha from LDS).
// LDS holds only HALF of each trajectory: 16 KiB at CH_S=128 -> warm
// fraction 1.5x (vs 2.0x) = 25% fewer sweep steps than CH_S=64 designs.
__global__ __launch_bounds__(128, 5)
void bcjr_fused_kernel(const float* __restrict__ llr_ch,   // [B][2*T]
                       const float* __restrict__ llr_a,    // [B][T]
                       float* __restrict__ out)            // [B][T]
{
    __shared__ unsigned short alds[HF * NSTATE];   // 8 KiB: alpha_t,   t in [t0, t0+64)
    __shared__ unsigned short blds[HF * NSTATE];   // 8 KiB: beta_{t+1}, t in [t0+64, t0+128)

    const int lane  = threadIdx.x & 63;
    const int role  = threadIdx.x >> 6;
    const int unit  = blockIdx.x;
    const int chunk = unit & (NCHUNK - 1);
    const int b     = unit >> 4;

    const float c0 = 1.0f - 2.0f * (float)(__popc(lane & 57) & 1);
    const float c1 = 1.0f - 2.0f * (float)(__popc(lane & 27) & 1);
    const float kE = 0.5f * 1.442695040888963f;
    const float k0 = kE * c0, k1 = kE * c1;

    const float* chp = llr_ch + (size_t)b * (2 * T_LEN);
    const float* lap = llr_a  + (size_t)b * T_LEN;
    float* outp = out + (size_t)b * T_LEN;
    const int t0 = chunk * CH_S;

    if (role == 0) {
        // ---- forward wave ----
        const int fselb = (2 * (lane & 31) + (lane >> 5)) << 2;
        float state = (chunk == 0) ? ((lane == 0) ? 1.0f : 0.0f) : (1.0f / 64.0f);
        const int ts = (chunk == 0) ? t0 : t0 - WARM;
        for (int g = ts; g < t0; g += RK)
            state = fwd_group<0>(state, chp, lap, alds, blds, outp, g, t0, lane, kE, k0, k1, fselb);
        for (int g = t0; g < t0 + HF; g += RK)
            state = fwd_group<1>(state, chp, lap, alds, blds, outp, g, t0, lane, kE, k0, k1, fselb);
        __syncthreads();   // alpha(H0) published, beta(H1) ready
        for (int g = t0 + HF; g < t0 + CH_S; g += RK)
            state = fwd_group<2>(state, chp, lap, alds, blds, outp, g, t0, lane, kE, k0, k1, fselb);
    } else {
        // ---- backward wave ----
        const unsigned pmask = (unsigned)(lane & 1) << 31;
        const int bgb = ((lane >> 1) + ((lane & 1) << 5)) << 2;  // src lane * 4
        float state = 1.0f / 64.0f;          // exact beta_T for the last chunk
        const int te = (chunk == NCHUNK - 1) ? (t0 + CH_S) : (t0 + CH_S + WARM);
        for (int g = te - RK; g >= t0 + CH_S; g -= RK)
            state = bwd_group<0>(state, chp, lap, alds, blds, outp, g, t0, lane, kE, k0, k1, pmask, bgb);
        for (int g = t0 + CH_S - RK; g >= t0 + HF; g -= RK)
            state = bwd_group<1>(state, chp, lap, alds, blds, outp, g, t0, lane, kE, k0, k1, pmask, bgb);
        __syncthreads();   // beta(H1) published, alpha(H0) ready
        for (int g = t0 + HF - RK; g >= t0; g -= RK)
            state = bwd_group<2>(state, chp, lap, alds, blds, outp, g, t0, lane, kE, k0, k1, pmask, bgb);
    }
}

extern "C" void kernel_launch(void* const* d_in, const int* in_sizes, int n_in,
                              void* d_out, int out_size, void* d_ws, size_t ws_size,
                              hipStream_t stream) {
    const float* llr_ch = (const float*)d_in[0];
    const float* llr_a  = (const float*)d_in[1];
    float* out = (float*)d_out;

    int B = in_sizes[0] / (2 * T_LEN);   // 256
    (void)d_ws; (void)ws_size;

    int n_units = B * NCHUNK;            // 4096 blocks (1 chunk each, 2 waves)
    hipLaunchKernelGGL(bcjr_fused_kernel, dim3(n_units), dim3(128), 0, stream,
                       llr_ch, llr_a, out);
}

// Round 9
// 128.962 us; speedup vs baseline: 1.2642x; 1.0201x over previous
//
#include <hip/hip_runtime.h>

#define T_LEN 2048
#define NSTATE 64
#define NCHUNK 16
#define CH_S 128      // stored steps per chunk
#define HF 64         // half of stored region (LDS depth per trajectory)
#define WARM 64       // warm-up steps before/after the stored region
#define RK 16         // renorm every 16 steps (scale cancels in LLR)
#define ROWQ 36       // dwords per LDS row (72 ushorts = 144B): 16B-aligned rows

// v_add_f32 with DPP-modified src: single fused VALU instr, no DS op.
template<int CTRL>
__device__ __forceinline__ float dpp_add(float v) {
    int r = __builtin_amdgcn_update_dpp(0, __float_as_int(v), CTRL, 0xF, 0xF, true);
    return v + __int_as_float(r);
}

// v_mov_b32_dpp quad_perm [1,0,3,2]: value of lane^1 — VALU, no DS op.
__device__ __forceinline__ float dpp_mov_xor1(float v) {
    return __int_as_float(__builtin_amdgcn_update_dpp(0, __float_as_int(v), 0xB1, 0xF, 0xF, true));
}

// Pure-DPP 64-lane sum to lane 63 (row_shr 1,2,4,8 + row_bcast15/31). Zero DS.
__device__ __forceinline__ float dpp_sum_to63(float v) {
    v = dpp_add<0x111>(v);
    v = dpp_add<0x112>(v);
    v = dpp_add<0x114>(v);
    v = dpp_add<0x118>(v);
    v = dpp_add<0x142>(v);
    v = dpp_add<0x143>(v);
    return v;
}

// Full-wave sum broadcast via v_readlane — zero DS ops.
__device__ __forceinline__ float wave_total(float v) {
    float s = dpp_sum_to63(v);
    return __int_as_float(__builtin_amdgcn_readlane(__float_as_int(s), 63));
}

// v + v[lane^1] via DPP quad_perm [1,0,3,2].
__device__ __forceinline__ float pair_sum_xor1(float v) {
    int r = __builtin_amdgcn_update_dpp(0, __float_as_int(v), 0xB1, 0xF, 0xF, true);
    return v + __int_as_float(r);
}

// raw bpermute: addrb is BYTE address (src_lane*4)
__device__ __forceinline__ float bperm(int addrb, float v) {
    return __int_as_float(__builtin_amdgcn_ds_bpermute(addrb, __float_as_int(v)));
}

// cheap fp32 -> bf16 (round-half-up)
__device__ __forceinline__ unsigned bf16_of(float f) {
    return (__float_as_uint(f) + 0x8000u) >> 16;
}
// unpack bf16 half (compile-time hi) of a packed dword
template<int HI>
__device__ __forceinline__ float bf16_half(unsigned w) {
    return __uint_as_float(HI ? (w & 0xffff0000u) : (w << 16));
}

// GEN_POLY = ('1111001','1011011'), mu=6, NS=64.
// o0 parity mask 57, o1 mask 27. x_s = kE*(la + c0(s)*l0 + c1(s)*l1),
// gamma(s,0)=2^x, gamma(s,1)=2^-x, to(s,b)=(b<<5)|(s>>1), kE=0.5*log2(e).
//
// LDS layout (transposed + padded): row = state/lane (64 rows), col = step
// within the stored half, bf16-packed 2/dword, row stride ROWQ=36 dwords.
// Producer: ONE ds_write_b128 per 8 steps (8 states packed in 4 dwords).
// Consumer: ONE/TWO ds_read_b128 per 8 steps. Only DS op left per step on
// the recurrence chain is the single state bpermute.

// ---- fwd 16-step group. MODE: 0=light, 1=store alpha(H0), 2=heavy LLR(H1) ----
template<int MODE>
__device__ __forceinline__ float fwd_group(float state,
                                           const float* __restrict__ chp,
                                           const float* __restrict__ lap,
                                           unsigned* __restrict__ alds,
                                           const unsigned* __restrict__ blds,
                                           float* __restrict__ outp,
                                           int g, int t0, int lane,
                                           float kE, float k0, float k1,
                                           int fselb)
{
    #pragma unroll
    for (int h = 0; h < 2; ++h) {
        const int gb = g + 8 * h;
        const float4* c4 = (const float4*)(chp + 2 * gb);
        const float4* a4 = (const float4*)(lap + gb);
        float4 cc[4], aa[2];
        #pragma unroll
        for (int i = 0; i < 4; ++i) cc[i] = c4[i];
        #pragma unroll
        for (int i = 0; i < 2; ++i) aa[i] = a4[i];
        uint4 bw0, bw1;
        if (MODE == 2) {
            // beta_{t+1} for the 8 steps: 2 vector reads (rows m and 32+m)
            const int off = (gb - t0 - HF) >> 1;
            bw0 = *(const uint4*)(blds + (lane >> 1) * ROWQ + off);
            bw1 = *(const uint4*)(blds + (32 + (lane >> 1)) * ROWQ + off);
        }
        unsigned pk[4];
        #pragma unroll
        for (int i = 0; i < 8; ++i) {
            float l0 = (i & 1) ? cc[i >> 1].z : cc[i >> 1].x;
            float l1 = (i & 1) ? cc[i >> 1].w : cc[i >> 1].y;
            float la = ((const float*)aa)[i];
            if (MODE == 1) {                       // ascending: even i first (=), odd ORs
                unsigned hs = bf16_of(state);
                if (i & 1) pk[i >> 1] |= hs << 16; else pk[i >> 1] = hs;
            }
            float x   = fmaf(la, kE, fmaf(l0, k0, l1 * k1));
            float g0v = exp2f(x);
            float g1v = __builtin_amdgcn_rcpf(g0v);
            float sg0 = state * g0v;               // alpha_t[s]*gamma0(s)
            float sg1 = state * g1v;               // alpha_t[s]*gamma1(s)
            if (MODE == 2) {
                unsigned w0 = (&bw0.x)[i >> 1];
                unsigned w1 = (&bw1.x)[i >> 1];
                float b0v = (i & 1) ? bf16_half<1>(w0) : bf16_half<0>(w0);
                float b1v = (i & 1) ? bf16_half<1>(w1) : bf16_half<0>(w1);
                float na = dpp_sum_to63(sg0 * b0v);     // n0 total -> lane 63
                float nb = dpp_sum_to63(sg1 * b1v);     // n1 total -> lane 63
                if (lane == 63)
                    outp[gb + i] = (__log2f(na) - __log2f(nb)) * 0.6931471805599453f;
            }
            float s0 = pair_sum_xor1(sg0);
            float s1 = pair_sum_xor1(sg1);
            float v  = (lane & 1) ? s1 : s0;       // even lane: s0, odd: s1
            state = bperm(fselb, v);               // dest j <- lane 2(j&31)+(j>>5)
        }
        if (MODE == 1)
            *(uint4*)(alds + lane * ROWQ + ((gb - t0) >> 1)) =
                make_uint4(pk[0], pk[1], pk[2], pk[3]);
    }
    float s = wave_total(state);
    return state * __builtin_amdgcn_rcpf(s);
}

// ---- bwd 16-step group. MODE: 0=light, 1=store beta(H1), 2=heavy LLR(H0) ----
template<int MODE>
__device__ __forceinline__ float bwd_group(float state,
                                           const float* __restrict__ chp,
                                           const float* __restrict__ lap,
                                           const unsigned* __restrict__ alds,
                                           unsigned* __restrict__ blds,
                                           float* __restrict__ outp,
                                           int g, int t0, int lane,
                                           float kE, float k0, float k1,
                                           unsigned pmask, int bgb)
{
    const bool odd = (lane & 1);
    #pragma unroll
    for (int h = 1; h >= 0; --h) {
        const int gb = g + 8 * h;
        const float4* c4 = (const float4*)(chp + 2 * gb);
        const float4* a4 = (const float4*)(lap + gb);
        float4 cc[4], aa[2];
        #pragma unroll
        for (int i = 0; i < 4; ++i) cc[i] = c4[i];
        #pragma unroll
        for (int i = 0; i < 2; ++i) aa[i] = a4[i];
        uint4 aw;
        if (MODE == 2)   // alpha_t for the 8 steps: ONE vector read (row lane)
            aw = *(const uint4*)(alds + lane * ROWQ + ((gb - t0) >> 1));
        unsigned pk[4];
        #pragma unroll
        for (int i = 7; i >= 0; --i) {
            float l0 = (i & 1) ? cc[i >> 1].z : cc[i >> 1].x;
            float l1 = (i & 1) ? cc[i >> 1].w : cc[i >> 1].y;
            float la = ((const float*)aa)[i];
            if (MODE == 1) {
                // DESCENDING loop: odd i visited FIRST -> it must INITIALIZE
                // the dword; even i (visited second) ORs the low half.
                // (Round-8 bug: roles were swapped -> garbage high halves.)
                unsigned hs = bf16_of(state);
                if (i & 1) pk[i >> 1] = hs << 16; else pk[i >> 1] |= hs;
            }
            float x  = fmaf(la, kE, fmaf(l0, k0, l1 * k1));
            float xg = __uint_as_float(__float_as_uint(x) ^ pmask);
            float ga  = exp2f(xg);                     // even: gamma0, odd: gamma1
            float gb_ = __builtin_amdgcn_rcpf(ga);     // even: gamma1, odd: gamma0
            float a  = bperm(bgb, state);              // even: beta[m], odd: beta[m+32]
            float bb = dpp_mov_xor1(a);                // partner value
            float u0 = ga * a;
            float u1 = gb_ * bb;
            if (MODE == 2) {
                unsigned w = (&aw.x)[i >> 1];
                float av = (i & 1) ? bf16_half<1>(w) : bf16_half<0>(w);
                float ua = odd ? u1 : u0;              // gamma0*beta[to0(s)]
                float ub = odd ? u0 : u1;              // gamma1*beta[to1(s)]
                float na = dpp_sum_to63(av * ua);      // n0 total -> lane 63
                float nb = dpp_sum_to63(av * ub);      // n1 total -> lane 63
                if (lane == 63)
                    outp[gb + i] = (__log2f(na) - __log2f(nb)) * 0.6931471805599453f;
            }
            state = u0 + u1;                           // beta_t
        }
        if (MODE == 1)
            *(uint4*)(blds + lane * ROWQ + ((gb - t0 - HF) >> 1)) =
                make_uint4(pk[0], pk[1], pk[2], pk[3]);
    }
    float s = wave_total(state);
    return state * __builtin_amdgcn_rcpf(s);
}

// ---------------- Fused kernel: staggered half-chunks ----------------
// Segment A (balanced, 128 steps each): fwd = warm + stored-H0 (alpha->LDS);
//                                       bwd = warm + stored-H1 (beta->LDS).
// Barrier.
// Segment B (balanced, 64 steps each):  fwd sweeps H1 w/ inline LLR (beta
//                                       from LDS); bwd sweeps H0 likewise.
__global__ __launch_bounds__(128, 4)
void bcjr_fused_kernel(const float* __restrict__ llr_ch,   // [B][2*T]
                       const float* __restrict__ llr_a,    // [B][T]
                       float* __restrict__ out)            // [B][T]
{
    __shared__ __align__(16) unsigned alds[NSTATE * ROWQ];   // 9216 B: alpha(H0)
    __shared__ __align__(16) unsigned blds[NSTATE * ROWQ];   // 9216 B: beta(H1)

    const int lane  = threadIdx.x & 63;
    const int role  = threadIdx.x >> 6;
    const int unit  = blockIdx.x;
    const int chunk = unit & (NCHUNK - 1);
    const int b     = unit >> 4;

    const float c0 = 1.0f - 2.0f * (float)(__popc(lane & 57) & 1);
    const float c1 = 1.0f - 2.0f * (float)(__popc(lane & 27) & 1);
    const float kE = 0.5f * 1.442695040888963f;
    const float k0 = kE * c0, k1 = kE * c1;

    const float* chp = llr_ch + (size_t)b * (2 * T_LEN);
    const float* lap = llr_a  + (size_t)b * T_LEN;
    float* outp = out + (size_t)b * T_LEN;
    const int t0 = chunk * CH_S;

    if (role == 0) {
        // ---- forward wave ----
        const int fselb = (2 * (lane & 31) + (lane >> 5)) << 2;
        float state = (chunk == 0) ? ((lane == 0) ? 1.0f : 0.0f) : (1.0f / 64.0f);
        const int ts = (chunk == 0) ? t0 : t0 - WARM;
        for (int g = ts; g < t0; g += RK)
            state = fwd_group<0>(state, chp, lap, alds, blds, outp, g, t0, lane, kE, k0, k1, fselb);
        for (int g = t0; g < t0 + HF; g += RK)
            state = fwd_group<1>(state, chp, lap, alds, blds, outp, g, t0, lane, kE, k0, k1, fselb);
        __syncthreads();   // alpha(H0) published, beta(H1) ready
        for (int g = t0 + HF; g < t0 + CH_S; g += RK)
            state = fwd_group<2>(state, chp, lap, alds, blds, outp, g, t0, lane, kE, k0, k1, fselb);
    } else {
        // ---- backward wave ----
        const unsigned pmask = (unsigned)(lane & 1) << 31;
        const int bgb = ((lane >> 1) + ((lane & 1) << 5)) << 2;  // src lane * 4
        float state = 1.0f / 64.0f;          // exact beta_T for the last chunk
        const int te = (chunk == NCHUNK - 1) ? (t0 + CH_S) : (t0 + CH_S + WARM);
        for (int g = te - RK; g >= t0 + CH_S; g -= RK)
            state = bwd_group<0>(state, chp, lap, alds, blds, outp, g, t0, lane, kE, k0, k1, pmask, bgb);
        for (int g = t0 + CH_S - RK; g >= t0 + HF; g -= RK)
            state = bwd_group<1>(state, chp, lap, alds, blds, outp, g, t0, lane, kE, k0, k1, pmask, bgb);
        __syncthreads();   // beta(H1) published, alpha(H0) ready
        for (int g = t0 + HF - RK; g >= t0; g -= RK)
            state = bwd_group<2>(state, chp, lap, alds, blds, outp, g, t0, lane, kE, k0, k1, pmask, bgb);
    }
}

extern "C" void kernel_launch(void* const* d_in, const int* in_sizes, int n_in,
                              void* d_out, int out_size, void* d_ws, size_t ws_size,
                              hipStream_t stream) {
    const float* llr_ch = (const float*)d_in[0];
    const float* llr_a  = (const float*)d_in[1];
    float* out = (float*)d_out;

    int B = in_sizes[0] / (2 * T_LEN);   // 256
    (void)d_ws; (void)ws_size;

    int n_units = B * NCHUNK;            // 4096 blocks (1 chunk each, 2 waves)
    hipLaunchKernelGGL(bcjr_fused_kernel, dim3(n_units), dim3(128), 0, stream,
                       llr_ch, llr_a, out);
}